// Round 7
// baseline (134.672 us; speedup 1.0000x reference)
//
#include <hip/hip_runtime.h>
#include <hip/hip_bf16.h>
#include <math.h>

#define VOCAB 100000
#define INPUT_DIM 100
#define HIDDEN_DIM 10
#define BATCH 1024
#define SEQ 512

// ---------------------------------------------------------------------------
// Kernel A: proj[v][i] = dot(emb[v][:], W_ih[i][:]) + b_ih[i] + b_hh[i]
// (biases folded here so the scan kernel saves instructions per step).
// One vocab row per thread; fully unrolled float4 loads. W_ih/biases are
// wave-uniform -> scalar cache. Memory-bound: 40 MB read + 4 MB write.
// proj layout [VOCAB][10] f32 (40 B rows, 4 MB) -> fits one XCD L2.
// ---------------------------------------------------------------------------
__global__ __launch_bounds__(128) void proj_kernel(
    const float* __restrict__ emb, const float* __restrict__ W_ih,
    const float* __restrict__ b_ih, const float* __restrict__ b_hh,
    float* __restrict__ proj) {
  int v = blockIdx.x * blockDim.x + threadIdx.x;
  if (v >= VOCAB) return;

  const float4* e4 = (const float4*)(emb + (size_t)v * INPUT_DIM);
  const float4* W4 = (const float4*)W_ih;  // [10][25] float4, uniform -> s_load

  float4 e[25];
#pragma unroll
  for (int d = 0; d < 25; ++d) e[d] = e4[d];

  float acc[HIDDEN_DIM];
#pragma unroll
  for (int i = 0; i < HIDDEN_DIM; ++i) acc[i] = b_ih[i] + b_hh[i];

#pragma unroll
  for (int d = 0; d < 25; ++d) {
#pragma unroll
    for (int i = 0; i < HIDDEN_DIM; ++i) {
      float4 w = W4[i * 25 + d];  // uniform
      acc[i] = fmaf(e[d].x, w.x, acc[i]);
      acc[i] = fmaf(e[d].y, w.y, acc[i]);
      acc[i] = fmaf(e[d].z, w.z, acc[i]);
      acc[i] = fmaf(e[d].w, w.w, acc[i]);
    }
  }

  // 40 B row = 5 float2 stores (8-B aligned for every v).
  float2* p2 = (float2*)(proj + (size_t)v * HIDDEN_DIM);
#pragma unroll
  for (int i = 0; i < 5; ++i) p2[i] = make_float2(acc[2 * i], acc[2 * i + 1]);
}

// ---------------------------------------------------------------------------
// Kernel B: the 512-step recurrence. One WAVE per batch element: 1024 waves
// = 1 wave per SIMD chip-wide (issue-bound: wall time/step ~= instrs/step
// x 2 cyc). Lane i<10 owns h[i]; h[j] broadcast via v_readlane. b is
// readfirstlane'd -> x loads provably uniform; group-uniform clamped bases
// keep the 8 index loads contiguous so they merge into s_load_dwordx8.
// 4-buffer rotating pipeline, 3 gather-groups outstanding (~670 cyc of
// compute between issue and use -> covers L2/L3 latency).
// Per step: 10 readlane + 1 mul + 9 FMA + 1 add + 1 max = 22 VALU instrs.
// Epilogue: FC + sigmoid, lane 0 writes out[b].
// ---------------------------------------------------------------------------
__global__ __launch_bounds__(256, 1) void scan_kernel(
    const int* __restrict__ x, const float* __restrict__ proj,
    const float* __restrict__ W_hh, const float* __restrict__ W_fc,
    const float* __restrict__ b_fc, float* __restrict__ out) {
  int lane = threadIdx.x & 63;
  int b = __builtin_amdgcn_readfirstlane(
      (int)((blockIdx.x * blockDim.x + threadIdx.x) >> 6));
  int i = (lane < HIDDEN_DIM) ? lane : 0;  // idle lanes shadow row 0

  float Wr[HIDDEN_DIM];
#pragma unroll
  for (int j = 0; j < HIDDEN_DIM; ++j) Wr[j] = W_hh[i * HIDDEN_DIM + j];
  float wfc = (lane < HIDDEN_DIM) ? W_fc[lane] : 0.f;

  const int* xb = x + (size_t)b * SEQ;
  float h = 0.f;

  // Group-uniform clamp keeps the 8 loads contiguous (mergeable into
  // s_load_dwordx8); past-end groups load valid garbage, never consumed.
#define LOADIDX(I, base)                                   \
  {                                                        \
    int base_c = (base) <= (SEQ - 8) ? (base) : (SEQ - 8); \
    _Pragma("unroll") for (int u = 0; u < 8; ++u)          \
      I[u] = xb[base_c + u];                               \
  }
#define GATHER(P, I)                                       \
  _Pragma("unroll") for (int u = 0; u < 8; ++u)            \
    P[u] = proj[(size_t)I[u] * HIDDEN_DIM + i];
#define COMPUTE(P)                                         \
  _Pragma("unroll") for (int u = 0; u < 8; ++u) {          \
    float hj[HIDDEN_DIM];                                  \
    _Pragma("unroll") for (int j = 0; j < HIDDEN_DIM; ++j) \
      hj[j] = __uint_as_float(                             \
          __builtin_amdgcn_readlane(__float_as_uint(h), j)); \
    float a0 = fmaf(Wr[0], hj[0], P[u]);                   \
    float a1 = Wr[1] * hj[1];                              \
    a0 = fmaf(Wr[2], hj[2], a0);                           \
    a1 = fmaf(Wr[3], hj[3], a1);                           \
    a0 = fmaf(Wr[4], hj[4], a0);                           \
    a1 = fmaf(Wr[5], hj[5], a1);                           \
    a0 = fmaf(Wr[6], hj[6], a0);                           \
    a1 = fmaf(Wr[7], hj[7], a1);                           \
    a0 = fmaf(Wr[8], hj[8], a0);                           \
    a1 = fmaf(Wr[9], hj[9], a1);                           \
    h = fmaxf(a0 + a1, 0.f);                               \
  }

  int iA[8], iB[8], iC[8], iD[8];
  float pA[8], pB[8], pC[8], pD[8];

  // Prologue: indices for groups 0..3; gathers in flight for groups 0..2.
  LOADIDX(iA, 0) LOADIDX(iB, 8) LOADIDX(iC, 16) LOADIDX(iD, 24)
  GATHER(pA, iA) GATHER(pB, iB) GATHER(pC, iC)

  // 64 groups, 4 per iteration. Phase g: issue gather(g+3), prefetch
  // idx(g+4), compute group g. Past-end issues are clamped (harmless).
  for (int tt = 0; tt < SEQ; tt += 32) {
    GATHER(pD, iD) LOADIDX(iA, tt + 32) COMPUTE(pA)
    GATHER(pA, iA) LOADIDX(iB, tt + 40) COMPUTE(pB)
    GATHER(pB, iB) LOADIDX(iC, tt + 48) COMPUTE(pC)
    GATHER(pC, iC) LOADIDX(iD, tt + 56) COMPUTE(pD)
  }
#undef LOADIDX
#undef GATHER
#undef COMPUTE

  // FC + sigmoid over lanes 0..9.
  float prod = wfc * h;
  float z = 0.f;
#pragma unroll
  for (int j = 0; j < HIDDEN_DIM; ++j)
    z += __uint_as_float(__builtin_amdgcn_readlane(__float_as_uint(prod), j));
  if (lane == 0) out[b] = 1.f / (1.f + expf(-(z + b_fc[0])));
}

extern "C" void kernel_launch(void* const* d_in, const int* in_sizes, int n_in,
                              void* d_out, int out_size, void* d_ws, size_t ws_size,
                              hipStream_t stream) {
  const int*   x    = (const int*)d_in[0];
  const float* emb  = (const float*)d_in[1];
  const float* W_ih = (const float*)d_in[2];
  const float* b_ih = (const float*)d_in[3];
  const float* W_hh = (const float*)d_in[4];
  const float* b_hh = (const float*)d_in[5];
  const float* W_fc = (const float*)d_in[6];
  const float* b_fc = (const float*)d_in[7];
  float* out = (float*)d_out;

  float* proj = (float*)d_ws;  // VOCAB*HIDDEN_DIM*4 = 4 MB scratch

  int blocksA = (VOCAB + 127) / 128;  // one vocab row per thread
  proj_kernel<<<blocksA, 128, 0, stream>>>(emb, W_ih, b_ih, b_hh, proj);

  int blocksB = (BATCH * 64) / 256;  // one wave per batch element
  scan_kernel<<<blocksB, 256, 0, stream>>>(x, proj, W_hh, W_fc, b_fc, out);
}

// Round 9
// 132.786 us; speedup vs baseline: 1.0142x; 1.0142x over previous
//
#include <hip/hip_runtime.h>
#include <hip/hip_bf16.h>
#include <math.h>

#define VOCAB 100000
#define INPUT_DIM 100
#define HIDDEN_DIM 10
#define BATCH 1024
#define SEQ 512

// ---------------------------------------------------------------------------
// Kernel A: proj[v][i] = dot(emb[v][:], W_ih[i][:]) + b_ih[i] + b_hh[i]
// (biases folded here so the scan kernel saves instructions per step).
// One vocab row per thread; fully unrolled float4 loads. W_ih/biases are
// wave-uniform -> scalar cache. Memory-bound: 40 MB read + 4 MB write.
// proj layout [VOCAB][10] f32 (40 B rows, 4 MB) -> fits one XCD L2.
// ---------------------------------------------------------------------------
__global__ __launch_bounds__(128) void proj_kernel(
    const float* __restrict__ emb, const float* __restrict__ W_ih,
    const float* __restrict__ b_ih, const float* __restrict__ b_hh,
    float* __restrict__ proj) {
  int v = blockIdx.x * blockDim.x + threadIdx.x;
  if (v >= VOCAB) return;

  const float4* e4 = (const float4*)(emb + (size_t)v * INPUT_DIM);
  const float4* W4 = (const float4*)W_ih;  // [10][25] float4, uniform -> s_load

  float4 e[25];
#pragma unroll
  for (int d = 0; d < 25; ++d) e[d] = e4[d];

  float acc[HIDDEN_DIM];
#pragma unroll
  for (int i = 0; i < HIDDEN_DIM; ++i) acc[i] = b_ih[i] + b_hh[i];

#pragma unroll
  for (int d = 0; d < 25; ++d) {
#pragma unroll
    for (int i = 0; i < HIDDEN_DIM; ++i) {
      float4 w = W4[i * 25 + d];  // uniform
      acc[i] = fmaf(e[d].x, w.x, acc[i]);
      acc[i] = fmaf(e[d].y, w.y, acc[i]);
      acc[i] = fmaf(e[d].z, w.z, acc[i]);
      acc[i] = fmaf(e[d].w, w.w, acc[i]);
    }
  }

  float2* p2 = (float2*)(proj + (size_t)v * HIDDEN_DIM);
#pragma unroll
  for (int i = 0; i < 5; ++i) p2[i] = make_float2(acc[2 * i], acc[2 * i + 1]);
}

// ---------------------------------------------------------------------------
// Kernel B: the 512-step recurrence. One WAVE per batch element (1024 waves
// = 1/SIMD chip-wide). Lane i<10 owns h[i]; h[j] broadcast via v_readlane.
//
// KEY FIX vs round 6 (the 134.7 us baseline): x indices are staged into LDS
// once per wave (2 coalesced int4 loads/lane). Per-phase index reads are
// ds_read_b128 on the LGKM counter, so the VM counter carries ONLY proj
// gathers. vmcnt decrements in issue order; with nothing interleaved,
// compute(g)'s wait for its 8 gathers leaves the 24 younger gathers
// (groups g+1..g+3) in flight -> true 3-phase (~1100 cyc) latency cover.
// ---------------------------------------------------------------------------
__global__ __launch_bounds__(256, 1) void scan_kernel(
    const int* __restrict__ x, const float* __restrict__ proj,
    const float* __restrict__ W_hh, const float* __restrict__ W_fc,
    const float* __restrict__ b_fc, float* __restrict__ out) {
  __shared__ int sIdx[4][SEQ];  // 8 KB: per-wave index row

  int lane = threadIdx.x & 63;
  int widx = threadIdx.x >> 6;  // wave within block, 0..3
  int b = __builtin_amdgcn_readfirstlane((int)(blockIdx.x * 4 + widx));
  int i = (lane < HIDDEN_DIM) ? lane : 0;  // idle lanes shadow row 0

  float Wr[HIDDEN_DIM];
#pragma unroll
  for (int j = 0; j < HIDDEN_DIM; ++j) Wr[j] = W_hh[i * HIDDEN_DIM + j];
  float wfc = (lane < HIDDEN_DIM) ? W_fc[lane] : 0.f;

  // Stage this wave's 512 indices into LDS (coalesced, once).
  const int4* xb4 = (const int4*)(x + (size_t)b * SEQ);
  int4* s4 = (int4*)(sIdx[widx]);
  s4[lane] = xb4[lane];            // ints 0..255
  s4[64 + lane] = xb4[64 + lane];  // ints 256..511
  // No barrier needed: each wave reads only LDS it wrote itself.

  const float* projLane = proj + i;  // per-lane base
  float h = 0.f;

  // Clamped group base keeps LDS reads in range; past-end groups fetch
  // valid tokens whose gathers are never consumed.
#define LOADIDX(Q0, Q1, base)                              \
  {                                                        \
    int bc_ = (base) <= (SEQ - 8) ? (base) : (SEQ - 8);    \
    Q0 = s4[bc_ >> 2];                                     \
    Q1 = s4[(bc_ >> 2) + 1];                               \
  }
#define GATHER(P, Q0, Q1)                                  \
  P[0] = projLane[(unsigned)Q0.x * 10u];                   \
  P[1] = projLane[(unsigned)Q0.y * 10u];                   \
  P[2] = projLane[(unsigned)Q0.z * 10u];                   \
  P[3] = projLane[(unsigned)Q0.w * 10u];                   \
  P[4] = projLane[(unsigned)Q1.x * 10u];                   \
  P[5] = projLane[(unsigned)Q1.y * 10u];                   \
  P[6] = projLane[(unsigned)Q1.z * 10u];                   \
  P[7] = projLane[(unsigned)Q1.w * 10u];
#define COMPUTE(P)                                         \
  _Pragma("unroll") for (int u = 0; u < 8; ++u) {          \
    float hj[HIDDEN_DIM];                                  \
    _Pragma("unroll") for (int j = 0; j < HIDDEN_DIM; ++j) \
      hj[j] = __uint_as_float(                             \
          __builtin_amdgcn_readlane(__float_as_uint(h), j)); \
    float a0 = fmaf(Wr[0], hj[0], P[u]);                   \
    float a1 = Wr[1] * hj[1];                              \
    a0 = fmaf(Wr[2], hj[2], a0);                           \
    a1 = fmaf(Wr[3], hj[3], a1);                           \
    a0 = fmaf(Wr[4], hj[4], a0);                           \
    a1 = fmaf(Wr[5], hj[5], a1);                           \
    a0 = fmaf(Wr[6], hj[6], a0);                           \
    a1 = fmaf(Wr[7], hj[7], a1);                           \
    a0 = fmaf(Wr[8], hj[8], a0);                           \
    a1 = fmaf(Wr[9], hj[9], a1);                           \
    h = fmaxf(a0 + a1, 0.f);                               \
  }

  int4 Ia0, Ia1, Ib0, Ib1, Ic0, Ic1, Id0, Id1;
  float pA[8], pB[8], pC[8], pD[8];

  // Prologue: idx for groups 0..3; gathers in flight for groups 0..2.
  LOADIDX(Ia0, Ia1, 0) LOADIDX(Ib0, Ib1, 8) LOADIDX(Ic0, Ic1, 16)
  GATHER(pA, Ia0, Ia1) GATHER(pB, Ib0, Ib1) GATHER(pC, Ic0, Ic1)
  LOADIDX(Id0, Id1, 24)

  // 64 groups, 4 per iteration. Phase g: issue gather(g+3) [vmcnt only],
  // ds_read idx(g+4) [lgkmcnt only], compute group g.
  for (int tt = 0; tt < SEQ; tt += 32) {
    GATHER(pD, Id0, Id1) LOADIDX(Ia0, Ia1, tt + 32) COMPUTE(pA)
    GATHER(pA, Ia0, Ia1) LOADIDX(Ib0, Ib1, tt + 40) COMPUTE(pB)
    GATHER(pB, Ib0, Ib1) LOADIDX(Ic0, Ic1, tt + 48) COMPUTE(pC)
    GATHER(pC, Ic0, Ic1) LOADIDX(Id0, Id1, tt + 56) COMPUTE(pD)
  }
#undef LOADIDX
#undef GATHER
#undef COMPUTE

  // FC + sigmoid over lanes 0..9.
  float prod = wfc * h;
  float z = 0.f;
#pragma unroll
  for (int j = 0; j < HIDDEN_DIM; ++j)
    z += __uint_as_float(__builtin_amdgcn_readlane(__float_as_uint(prod), j));
  if (lane == 0) out[b] = 1.f / (1.f + expf(-(z + b_fc[0])));
}

extern "C" void kernel_launch(void* const* d_in, const int* in_sizes, int n_in,
                              void* d_out, int out_size, void* d_ws, size_t ws_size,
                              hipStream_t stream) {
  const int*   x    = (const int*)d_in[0];
  const float* emb  = (const float*)d_in[1];
  const float* W_ih = (const float*)d_in[2];
  const float* b_ih = (const float*)d_in[3];
  const float* W_hh = (const float*)d_in[4];
  const float* b_hh = (const float*)d_in[5];
  const float* W_fc = (const float*)d_in[6];
  const float* b_fc = (const float*)d_in[7];
  float* out = (float*)d_out;

  float* proj = (float*)d_ws;  // VOCAB*HIDDEN_DIM*4 = 4 MB scratch

  int blocksA = (VOCAB + 127) / 128;  // one vocab row per thread
  proj_kernel<<<blocksA, 128, 0, stream>>>(emb, W_ih, b_ih, b_hh, proj);

  int blocksB = BATCH / 4;  // 4 waves/block, one wave per batch element
  scan_kernel<<<blocksB, 256, 0, stream>>>(x, proj, W_hh, W_fc, b_fc, out);
}